// Round 2
// baseline (219.337 us; speedup 1.0000x reference)
//
#include <hip/hip_runtime.h>

static constexpr int HD = 128;      // head dim
static constexpr int HH = 64;       // height
static constexpr int WW = 64;       // width
static constexpr int ROWS = 4;      // rows per block
static constexpr int BLK = 256;     // threads per block
static constexpr int DCH = 16;      // d-chunk for LDS-staged writeout
static constexpr float SCALE = 0.08838834764831845f;  // 128^-0.5

__global__ __launch_bounds__(BLK) void natten3_kernel(
    const float* __restrict__ Q, const float* __restrict__ K,
    const float* __restrict__ V, float* __restrict__ O)
{
  __shared__ float lds[BLK][DCH + 1];   // +1 pad: conflict-free stride 17

  const int tid = threadIdx.x;
  const int w   = tid & (WW - 1);
  const int hr  = tid >> 6;             // 0..3
  const int bh  = blockIdx.x;           // 0..511
  const int b   = bh >> 4;
  const int h0  = (bh & 15) * ROWS;
  const int h   = h0 + hr;

  const int plane = HH * WW;                      // 4096
  const size_t img = (size_t)HD * plane;          // 524288
  const float* Qb = Q + (size_t)b * img;
  const float* Kb = K + (size_t)b * img;
  const float* Vb = V + (size_t)b * img;

  // 9 neighbor spatial offsets, clamped to valid addresses; float mask for fixup
  int   off[9];
  float msk[9];
  #pragma unroll
  for (int dh = 0; dh < 3; ++dh) {
    #pragma unroll
    for (int dw = 0; dw < 3; ++dw) {
      int r = h + dh - 1, c = w + dw - 1;
      const int j = dh * 3 + dw;
      const bool ok = (r >= 0) && (r < HH) && (c >= 0) && (c < WW);
      msk[j] = ok ? 1.0f : 0.0f;
      r = min(max(r, 0), HH - 1);
      c = min(max(c, 0), WW - 1);
      off[j] = r * WW + c;
    }
  }
  const int qoff = h * WW + w;

  // ---- Phase 1: logits (unmasked loads from clamped addresses) ----
  float logit[9];
  #pragma unroll
  for (int j = 0; j < 9; ++j) logit[j] = 0.0f;

  #pragma unroll 4
  for (int d = 0; d < HD; ++d) {
    const float* Kd = Kb + d * plane;
    const float qv = Qb[d * plane + qoff];
    #pragma unroll
    for (int j = 0; j < 9; ++j)
      logit[j] = fmaf(qv, Kd[off[j]], logit[j]);
  }

  // OOB neighbors: k was zero-padded in the reference -> logit exactly 0.
  #pragma unroll
  for (int j = 0; j < 9; ++j) logit[j] = msk[j] * logit[j] * SCALE;

  // ---- softmax over 9 (OOB logits = 0 participate in denominator) ----
  float m = logit[0];
  #pragma unroll
  for (int j = 1; j < 9; ++j) m = fmaxf(m, logit[j]);
  float att[9];
  float Z = 0.0f;
  #pragma unroll
  for (int j = 0; j < 9; ++j) { att[j] = __expf(logit[j] - m); Z += att[j]; }
  const float rZ = 1.0f / Z;
  // zero OOB attn so phase-2 clamped V loads contribute nothing (v zero-padded in ref)
  #pragma unroll
  for (int j = 0; j < 9; ++j) att[j] *= rZ * msk[j];

  // ---- Phase 2: PV, LDS-staged for coalesced [B,H,W,d] writes ----
  for (int cc = 0; cc < HD / DCH; ++cc) {
    #pragma unroll 4
    for (int dl = 0; dl < DCH; ++dl) {
      const float* Vd = Vb + (cc * DCH + dl) * plane;
      float o = 0.0f;
      #pragma unroll
      for (int j = 0; j < 9; ++j)
        o = fmaf(att[j], Vd[off[j]], o);
      lds[tid][dl] = o;
    }
    __syncthreads();
    // cooperative writeout: 256*16 floats; 16 consecutive lanes write one
    // pixel's 64B-aligned d-segment -> fully-written sectors
    #pragma unroll
    for (int i = 0; i < DCH; ++i) {
      const int f  = i * BLK + tid;
      const int px = f >> 4;           // / DCH
      const int dl = f & (DCH - 1);
      const int pw = px & (WW - 1);
      const int pr = px >> 6;
      const size_t oa = ((size_t)b * plane + (size_t)(h0 + pr) * WW + pw) * HD
                        + cc * DCH + dl;
      O[oa] = lds[px][dl];
    }
    __syncthreads();
  }
}

extern "C" void kernel_launch(void* const* d_in, const int* in_sizes, int n_in,
                              void* d_out, int out_size, void* d_ws, size_t ws_size,
                              hipStream_t stream) {
  const float* q = (const float*)d_in[0];
  const float* k = (const float*)d_in[1];
  const float* v = (const float*)d_in[2];
  float* o = (float*)d_out;
  const int nblocks = 32 * (HH / ROWS);   // 512
  natten3_kernel<<<dim3(nblocks), dim3(BLK), 0, stream>>>(q, k, v, o);
}

// Round 4
// 86.695 us; speedup vs baseline: 2.5300x; 2.5300x over previous
//
#include <hip/hip_runtime.h>

static constexpr int HD   = 128;   // head dim
static constexpr int HH   = 64;    // height
static constexpr int WW   = 64;    // width
static constexpr int ROWS = 4;     // rows per block
static constexpr int BLK  = 256;   // threads per block
static constexpr int DC   = 8;     // d-planes per chunk
static constexpr int NCH  = HD / DC;      // 16 chunks
static constexpr int HALO = ROWS + 2;     // 6 rows incl. halo
static constexpr int LSTR = 12;    // padded per-pixel plane stride (floats):
                                   // 16B-aligned float4 groups AND bank base
                                   // (12w+4g)%32 covers all 32 banks uniformly
static constexpr float SCALE = 0.08838834764831845f;  // 128^-0.5

__global__ __launch_bounds__(BLK) void natten3_kernel(
    const float* __restrict__ Q, const float* __restrict__ K,
    const float* __restrict__ V, float* __restrict__ O)
{
  __shared__ float buf[2][HALO * WW * LSTR];   // 2 x 18 KB, double-buffered
  __shared__ float ostg[BLK * (DC + 1)];       // 9 KB writeout staging

  const int tid = threadIdx.x;
  const int w   = tid & 63;
  const int hr  = tid >> 6;              // 0..3
  const int b   = blockIdx.x >> 4;
  const int h0  = (blockIdx.x & 15) * ROWS;
  const int h   = h0 + hr;

  const int plane = HH * WW;             // 4096
  const size_t img = (size_t)HD * plane;
  const float* Qb = Q + (size_t)b * img;
  const float* Kb = K + (size_t)b * img;
  const float* Vb = V + (size_t)b * img;
  const int qoff = h * WW + w;

  // ---- staging map: 768 float4-groups = 6 rows x 64 w x 2 p-groups, 3/thread
  // lanes share (row, pgroup), consecutive w -> coalesced global scalar loads,
  // conflict-free ds_write_b128.
  int sg_g[3];   // global offset (within image, chunk-invariant part)
  int sg_l[3];   // lds float offset
  #pragma unroll
  for (int it = 0; it < 3; ++it) {
    const int idx  = it * BLK + tid;
    const int ws   = idx & 63;
    const int rest = idx >> 6;           // 0..11
    const int is   = rest >> 1;          // 0..5 halo row
    const int gs   = rest & 1;           // p-group
    const int grow = min(max(h0 - 1 + is, 0), HH - 1);
    sg_g[it] = gs * 4 * plane + grow * WW + ws;
    sg_l[it] = (is * WW + ws) * LSTR + gs * 4;
  }

  // ---- per-pixel neighbor LDS offsets + validity masks
  int   lofs[9];
  float msk[9];
  #pragma unroll
  for (int dh = 0; dh < 3; ++dh) {
    #pragma unroll
    for (int dw = 0; dw < 3; ++dw) {
      const int j = dh * 3 + dw;
      const int r = h + dh - 1, c = w + dw - 1;
      msk[j] = (r >= 0 && r < HH && c >= 0 && c < WW) ? 1.0f : 0.0f;
      const int cc = min(max(c, 0), WW - 1);
      lofs[j] = ((hr + dh) * WW + cc) * LSTR;   // row hr+dh in halo coords
    }
  }

  // ================= Phase 1: logits =================
  // prologue: stage K chunk 0 into buf[0]
  {
    float s[3][4];
    #pragma unroll
    for (int it = 0; it < 3; ++it)
      #pragma unroll
      for (int p = 0; p < 4; ++p)
        s[it][p] = Kb[sg_g[it] + p * plane];
    #pragma unroll
    for (int it = 0; it < 3; ++it)
      *(float4*)&buf[0][sg_l[it]] = make_float4(s[it][0], s[it][1], s[it][2], s[it][3]);
  }
  __syncthreads();

  float logit[9];
  #pragma unroll
  for (int j = 0; j < 9; ++j) logit[j] = 0.0f;

  for (int c = 0; c < NCH; ++c) {
    const int cur = c & 1;
    // issue next chunk's staging loads early (latency hides under compute)
    float s[3][4];
    if (c + 1 < NCH) {
      const int dbase = (c + 1) * DC * plane;
      #pragma unroll
      for (int it = 0; it < 3; ++it)
        #pragma unroll
        for (int p = 0; p < 4; ++p)
          s[it][p] = Kb[dbase + sg_g[it] + p * plane];
    }
    // Q for this chunk (coalesced scalar, own pixel)
    float q[DC];
    #pragma unroll
    for (int p = 0; p < DC; ++p)
      q[p] = Qb[(c * DC + p) * plane + qoff];
    // compute from buf[cur]
    const float* __restrict__ bc = buf[cur];
    #pragma unroll
    for (int j = 0; j < 9; ++j) {
      const float4 ka = *(const float4*)&bc[lofs[j]];
      const float4 kb = *(const float4*)&bc[lofs[j] + 4];
      float acc = logit[j];
      acc = fmaf(q[0], ka.x, acc); acc = fmaf(q[1], ka.y, acc);
      acc = fmaf(q[2], ka.z, acc); acc = fmaf(q[3], ka.w, acc);
      acc = fmaf(q[4], kb.x, acc); acc = fmaf(q[5], kb.y, acc);
      acc = fmaf(q[6], kb.z, acc); acc = fmaf(q[7], kb.w, acc);
      logit[j] = acc;
    }
    // write next buffer (other waves finished reading it last iteration)
    if (c + 1 < NCH) {
      #pragma unroll
      for (int it = 0; it < 3; ++it)
        *(float4*)&buf[cur ^ 1][sg_l[it]] = make_float4(s[it][0], s[it][1], s[it][2], s[it][3]);
    }
    __syncthreads();
  }

  // ---- softmax over 9 (OOB logits = 0 participate in denominator)
  #pragma unroll
  for (int j = 0; j < 9; ++j) logit[j] = msk[j] * logit[j] * SCALE;
  float m = logit[0];
  #pragma unroll
  for (int j = 1; j < 9; ++j) m = fmaxf(m, logit[j]);
  float att[9];
  float Z = 0.0f;
  #pragma unroll
  for (int j = 0; j < 9; ++j) { att[j] = __expf(logit[j] - m); Z += att[j]; }
  const float rZ = 1.0f / Z;
  #pragma unroll
  for (int j = 0; j < 9; ++j) att[j] *= rZ * msk[j];

  // ================= Phase 2: PV =================
  // stage V chunk 0 into buf[0] (all waves done reading buf[0] at last barrier)
  {
    float s[3][4];
    #pragma unroll
    for (int it = 0; it < 3; ++it)
      #pragma unroll
      for (int p = 0; p < 4; ++p)
        s[it][p] = Vb[sg_g[it] + p * plane];
    #pragma unroll
    for (int it = 0; it < 3; ++it)
      *(float4*)&buf[0][sg_l[it]] = make_float4(s[it][0], s[it][1], s[it][2], s[it][3]);
  }
  __syncthreads();

  const size_t obase = ((size_t)b * plane + h0 * WW) * HD;
  for (int c = 0; c < NCH; ++c) {
    const int cur = c & 1;
    float s[3][4];
    if (c + 1 < NCH) {
      const int dbase = (c + 1) * DC * plane;
      #pragma unroll
      for (int it = 0; it < 3; ++it)
        #pragma unroll
        for (int p = 0; p < 4; ++p)
          s[it][p] = Vb[dbase + sg_g[it] + p * plane];
    }
    // PV for this chunk
    float o[DC];
    #pragma unroll
    for (int p = 0; p < DC; ++p) o[p] = 0.0f;
    const float* __restrict__ bc = buf[cur];
    #pragma unroll
    for (int j = 0; j < 9; ++j) {
      const float4 va = *(const float4*)&bc[lofs[j]];
      const float4 vb = *(const float4*)&bc[lofs[j] + 4];
      const float a = att[j];
      o[0] = fmaf(a, va.x, o[0]); o[1] = fmaf(a, va.y, o[1]);
      o[2] = fmaf(a, va.z, o[2]); o[3] = fmaf(a, va.w, o[3]);
      o[4] = fmaf(a, vb.x, o[4]); o[5] = fmaf(a, vb.y, o[5]);
      o[6] = fmaf(a, vb.z, o[6]); o[7] = fmaf(a, vb.w, o[7]);
    }
    // stage output chunk for coalesced [B,H,W,d] writes
    #pragma unroll
    for (int p = 0; p < DC; ++p) ostg[tid * (DC + 1) + p] = o[p];
    __syncthreads();   // A: ostg written; buf[cur] reads done
    // cooperative writeout: 2048 floats, 8/thread
    #pragma unroll
    for (int i = 0; i < DC; ++i) {
      const int f  = i * BLK + tid;
      const int px = f >> 3;           // 0..255 pixel within tile
      const int dl = f & 7;
      O[obase + (size_t)px * HD + c * DC + dl] = ostg[px * (DC + 1) + dl];
    }
    if (c + 1 < NCH) {
      #pragma unroll
      for (int it = 0; it < 3; ++it)
        *(float4*)&buf[cur ^ 1][sg_l[it]] = make_float4(s[it][0], s[it][1], s[it][2], s[it][3]);
    }
    __syncthreads();   // B: buf[nxt] visible; ostg reads done
  }
}

extern "C" void kernel_launch(void* const* d_in, const int* in_sizes, int n_in,
                              void* d_out, int out_size, void* d_ws, size_t ws_size,
                              hipStream_t stream) {
  const float* q = (const float*)d_in[0];
  const float* k = (const float*)d_in[1];
  const float* v = (const float*)d_in[2];
  float* o = (float*)d_out;
  const int nblocks = 32 * (HH / ROWS);   // 512
  natten3_kernel<<<dim3(nblocks), dim3(BLK), 0, stream>>>(q, k, v, o);
}

// Round 5
// 65.506 us; speedup vs baseline: 3.3483x; 1.3235x over previous
//
#include <hip/hip_runtime.h>

static constexpr int HD   = 128;   // head dim
static constexpr int HH   = 64;    // height
static constexpr int WW   = 64;    // width
static constexpr int ROWS = 2;     // tile rows per block
static constexpr int BLK  = 256;   // threads: 2 per pixel (d-halves)
static constexpr int HALO = ROWS + 2;     // 4 halo rows
static constexpr int LSTR = 12;    // LDS per-pixel plane stride (floats):
                                   // 16B-aligned groups; (12w+4g)%32 uniform banks
static constexpr int OSTR = 20;    // ostg per-pixel stride (floats), 16B-aligned
static constexpr int NCH  = 16;    // chunks of 8 planes (4 per half)
static constexpr float SCALE = 0.08838834764831845f;  // 128^-0.5

// Split-d: thread (px, hf) handles planes d = c*8 + 4*hf + p, p<4, c<16.
// Pairs (2m,2m+1) share a pixel -> logit reduce = shfl_xor(1).
__global__ __launch_bounds__(BLK, 4) void natten3_kernel(
    const float* __restrict__ Q, const float* __restrict__ K,
    const float* __restrict__ V, float* __restrict__ O)
{
  __shared__ float buf[2][HALO * WW * LSTR];  // 2 x 12 KB, double-buffered
  __shared__ float ostg[ROWS * WW * OSTR];    // 10 KB, 2-chunk writeout staging

  const int tid = threadIdx.x;
  const int hf  = tid & 1;               // d-half
  const int px  = tid >> 1;              // 0..127 pixel in tile
  const int w   = px & 63;
  const int pr  = px >> 6;               // tile row 0/1

  // XCD-chunked swizzle: 1024 blocks, 128 consecutive tiles (4 images) per XCD
  const int bid = blockIdx.x;
  const int swz = (bid & 7) * 128 + (bid >> 3);
  const int b   = swz >> 5;              // image
  const int h0  = (swz & 31) * ROWS;     // tile top row
  const int hh  = h0 + pr;               // my pixel's global row

  const int plane = HH * WW;             // 4096
  const size_t img = (size_t)HD * plane;
  const float* Qb = Q + (size_t)b * img;
  const float* Kb = K + (size_t)b * img;
  const float* Vb = V + (size_t)b * img;
  const int qoff = hh * WW + w;
  const int dho  = 4 * hf;               // my half's offset within an 8-chunk

  // staging map: 512 float4-groups = 4 halo rows x 64 w x 2 pgroups, 2/thread
  // per wave all lanes share (row,pgroup), ws = lane -> coalesced + conflict-free
  int sg_g[2], sg_l[2];
  #pragma unroll
  for (int it = 0; it < 2; ++it) {
    const int idx  = it * BLK + tid;
    const int ws   = idx & 63;
    const int rest = idx >> 6;           // 0..7
    const int is   = rest >> 1;          // halo row 0..3
    const int gs   = rest & 1;           // plane group
    const int grow = min(max(h0 - 1 + is, 0), HH - 1);
    sg_g[it] = gs * 4 * plane + grow * WW + ws;
    sg_l[it] = (is * WW + ws) * LSTR + gs * 4;
  }

  // neighbor LDS offsets (my half's group) + validity masks
  int   lofs[9];
  float msk[9];
  #pragma unroll
  for (int dh = 0; dh < 3; ++dh) {
    #pragma unroll
    for (int dw = 0; dw < 3; ++dw) {
      const int j = dh * 3 + dw;
      const int r = hh + dh - 1, c = w + dw - 1;
      msk[j] = (r >= 0 && r < HH && c >= 0 && c < WW) ? 1.0f : 0.0f;
      const int cc = min(max(c, 0), WW - 1);
      lofs[j] = ((pr + dh) * WW + cc) * LSTR + dho;
    }
  }

  // ================= Phase 1: logits =================
  {
    float s[2][4];
    #pragma unroll
    for (int it = 0; it < 2; ++it)
      #pragma unroll
      for (int p = 0; p < 4; ++p)
        s[it][p] = Kb[sg_g[it] + p * plane];
    #pragma unroll
    for (int it = 0; it < 2; ++it)
      *(float4*)&buf[0][sg_l[it]] = make_float4(s[it][0], s[it][1], s[it][2], s[it][3]);
  }
  float q[4];
  #pragma unroll
  for (int p = 0; p < 4; ++p) q[p] = Qb[(dho + p) * plane + qoff];
  __syncthreads();

  float logit[9];
  #pragma unroll
  for (int j = 0; j < 9; ++j) logit[j] = 0.0f;

  for (int c = 0; c < NCH; ++c) {
    const int cur = c & 1;
    float s[2][4], qn[4];
    if (c + 1 < NCH) {           // issue next chunk's loads early
      const int dbase = (c + 1) * 8 * plane;
      #pragma unroll
      for (int it = 0; it < 2; ++it)
        #pragma unroll
        for (int p = 0; p < 4; ++p)
          s[it][p] = Kb[dbase + sg_g[it] + p * plane];
      #pragma unroll
      for (int p = 0; p < 4; ++p)
        qn[p] = Qb[((c + 1) * 8 + dho + p) * plane + qoff];
    }
    const float* __restrict__ bc = buf[cur];
    #pragma unroll
    for (int j = 0; j < 9; ++j) {
      const float4 k4 = *(const float4*)&bc[lofs[j]];
      float acc = logit[j];
      acc = fmaf(q[0], k4.x, acc); acc = fmaf(q[1], k4.y, acc);
      acc = fmaf(q[2], k4.z, acc); acc = fmaf(q[3], k4.w, acc);
      logit[j] = acc;
    }
    if (c + 1 < NCH) {
      #pragma unroll
      for (int it = 0; it < 2; ++it)
        *(float4*)&buf[cur ^ 1][sg_l[it]] = make_float4(s[it][0], s[it][1], s[it][2], s[it][3]);
      #pragma unroll
      for (int p = 0; p < 4; ++p) q[p] = qn[p];
    }
    __syncthreads();
  }

  // pair-reduce partial logits across the two d-halves (lanes 2m,2m+1)
  #pragma unroll
  for (int j = 0; j < 9; ++j) logit[j] += __shfl_xor(logit[j], 1);

  // softmax over 9 (OOB logits = 0 participate in denominator)
  #pragma unroll
  for (int j = 0; j < 9; ++j) logit[j] = msk[j] * logit[j] * SCALE;
  float m = logit[0];
  #pragma unroll
  for (int j = 1; j < 9; ++j) m = fmaxf(m, logit[j]);
  float att[9];
  float Z = 0.0f;
  #pragma unroll
  for (int j = 0; j < 9; ++j) { att[j] = __expf(logit[j] - m); Z += att[j]; }
  const float rZ = 1.0f / Z;
  #pragma unroll
  for (int j = 0; j < 9; ++j) att[j] *= rZ * msk[j];

  // ================= Phase 2: PV =================
  {
    float s[2][4];
    #pragma unroll
    for (int it = 0; it < 2; ++it)
      #pragma unroll
      for (int p = 0; p < 4; ++p)
        s[it][p] = Vb[sg_g[it] + p * plane];
    #pragma unroll
    for (int it = 0; it < 2; ++it)
      *(float4*)&buf[0][sg_l[it]] = make_float4(s[it][0], s[it][1], s[it][2], s[it][3]);
  }
  __syncthreads();

  const size_t obase = ((size_t)b * plane + (size_t)h0 * WW) * HD;
  for (int c = 0; c < NCH; ++c) {
    const int cur = c & 1;
    float s[2][4];
    if (c + 1 < NCH) {
      const int dbase = (c + 1) * 8 * plane;
      #pragma unroll
      for (int it = 0; it < 2; ++it)
        #pragma unroll
        for (int p = 0; p < 4; ++p)
          s[it][p] = Vb[dbase + sg_g[it] + p * plane];
    }
    float o0 = 0.f, o1 = 0.f, o2 = 0.f, o3 = 0.f;
    const float* __restrict__ bc = buf[cur];
    #pragma unroll
    for (int j = 0; j < 9; ++j) {
      const float4 v4 = *(const float4*)&bc[lofs[j]];
      const float a = att[j];
      o0 = fmaf(a, v4.x, o0); o1 = fmaf(a, v4.y, o1);
      o2 = fmaf(a, v4.z, o2); o3 = fmaf(a, v4.w, o3);
    }
    // stage my 4 planes: local d within 2-chunk group = (c&1)*8 + 4*hf + p
    *(float4*)&ostg[px * OSTR + (c & 1) * 8 + dho] = make_float4(o0, o1, o2, o3);

    if (c & 1) {
      __syncthreads();   // ostg complete for the pair; buf[cur] reads done
      // writeout: 16 consecutive d per pixel = full 64B sectors
      const size_t oa = obase + (size_t)px * HD + (c >> 1) * 16 + hf * 8;
      const float4 wa = *(const float4*)&ostg[px * OSTR + hf * 8];
      const float4 wb = *(const float4*)&ostg[px * OSTR + hf * 8 + 4];
      *(float4*)&O[oa]     = wa;
      *(float4*)&O[oa + 4] = wb;
      if (c + 1 < NCH) {
        #pragma unroll
        for (int it = 0; it < 2; ++it)
          *(float4*)&buf[cur ^ 1][sg_l[it]] = make_float4(s[it][0], s[it][1], s[it][2], s[it][3]);
      }
      __syncthreads();
    } else {
      #pragma unroll
      for (int it = 0; it < 2; ++it)
        *(float4*)&buf[cur ^ 1][sg_l[it]] = make_float4(s[it][0], s[it][1], s[it][2], s[it][3]);
      __syncthreads();
    }
  }
}

extern "C" void kernel_launch(void* const* d_in, const int* in_sizes, int n_in,
                              void* d_out, int out_size, void* d_ws, size_t ws_size,
                              hipStream_t stream) {
  const float* q = (const float*)d_in[0];
  const float* k = (const float*)d_in[1];
  const float* v = (const float*)d_in[2];
  float* o = (float*)d_out;
  const int nblocks = 32 * (HH / ROWS);   // 1024
  natten3_kernel<<<dim3(nblocks), dim3(BLK), 0, stream>>>(q, k, v, o);
}

// Round 6
// 46.556 us; speedup vs baseline: 4.7113x; 1.4070x over previous
//
#include <hip/hip_runtime.h>

static constexpr int HD   = 128;   // head dim
static constexpr int HH   = 64;    // height
static constexpr int WW   = 64;    // width
static constexpr int ROWS = 2;     // tile rows per block
static constexpr int BLK  = 512;   // 4 threads per pixel (d-quarters)
static constexpr int HALO = ROWS + 2;     // 4 halo rows
static constexpr int DC   = 16;    // d-planes per chunk
static constexpr int NCH  = HD / DC;      // 8 chunks
static constexpr int LSTR = 20;    // per-pixel plane stride: 16 used + 4 pad,
                                   // (20w+4g)%32 walks bank quads uniformly
static constexpr float SCALE = 0.08838834764831845f;  // 128^-0.5

// Thread (px, qf) owns planes d = c*16 + 4*qf + p (p<4) of pixel px.
// Quad lanes 4m..4m+3 share a pixel -> logit reduce = 2 shfl_xor.
__global__ __launch_bounds__(BLK, 4) void natten3_kernel(
    const float* __restrict__ Q, const float* __restrict__ K,
    const float* __restrict__ V, float* __restrict__ O)
{
  __shared__ float buf[2][HALO * WW * LSTR];   // 2 x 20 KB; 4 blocks = 160 KiB

  const int tid = threadIdx.x;
  const int qf  = tid & 3;               // d-quarter
  const int px  = tid >> 2;              // 0..127 pixel in tile
  const int w   = px & 63;
  const int pr  = px >> 6;               // tile row 0/1

  // XCD-chunked swizzle: 1024 blocks, 128 consecutive tiles per XCD
  const int bid = blockIdx.x;
  const int swz = (bid & 7) * 128 + (bid >> 3);
  const int b   = swz >> 5;              // image
  const int h0  = (swz & 31) * ROWS;     // tile top row
  const int hh  = h0 + pr;

  const int plane = HH * WW;             // 4096
  const size_t img = (size_t)HD * plane;
  const float* Qb = Q + (size_t)b * img;
  const float* Kb = K + (size_t)b * img;
  const float* Vb = V + (size_t)b * img;
  const int qoff = hh * WW + w;
  const int dq   = 4 * qf;               // my quarter's offset within a 16-chunk

  // staging map: 1024 float4-groups = 4 halo rows x 64 w x 4 pgroups, 2/thread
  // lanes of a wave share (row,pgroup), ws=lane -> coalesced global dwords,
  // uniform-bank LDS writes.
  int sg_g[2], sg_l[2];
  #pragma unroll
  for (int it = 0; it < 2; ++it) {
    const int idx  = it * BLK + tid;     // 0..1023
    const int ws   = idx & 63;
    const int rest = idx >> 6;           // 0..15
    const int is   = rest >> 2;          // halo row 0..3
    const int gs   = rest & 3;           // plane group 0..3
    const int grow = min(max(h0 - 1 + is, 0), HH - 1);
    sg_g[it] = gs * 4 * plane + grow * WW + ws;
    sg_l[it] = (is * WW + ws) * LSTR + gs * 4;
  }

  // neighbor LDS offsets (my quarter) + validity masks
  int   lofs[9];
  float msk[9];
  #pragma unroll
  for (int dh = 0; dh < 3; ++dh) {
    #pragma unroll
    for (int dw = 0; dw < 3; ++dw) {
      const int j = dh * 3 + dw;
      const int r = hh + dh - 1, c = w + dw - 1;
      msk[j] = (r >= 0 && r < HH && c >= 0 && c < WW) ? 1.0f : 0.0f;
      const int cc = min(max(c, 0), WW - 1);
      lofs[j] = ((pr + dh) * WW + cc) * LSTR + dq;
    }
  }

  // ================= Phase 1: logits =================
  {
    float s[2][4];
    #pragma unroll
    for (int it = 0; it < 2; ++it)
      #pragma unroll
      for (int p = 0; p < 4; ++p)
        s[it][p] = Kb[sg_g[it] + p * plane];
    #pragma unroll
    for (int it = 0; it < 2; ++it)
      *(float4*)&buf[0][sg_l[it]] = make_float4(s[it][0], s[it][1], s[it][2], s[it][3]);
  }
  float q[4];
  #pragma unroll
  for (int p = 0; p < 4; ++p) q[p] = Qb[(dq + p) * plane + qoff];
  __syncthreads();

  float logit[9];
  #pragma unroll
  for (int j = 0; j < 9; ++j) logit[j] = 0.0f;

  for (int c = 0; c < NCH; ++c) {
    const int cur = c & 1;
    float s[2][4], qn[4];
    if (c + 1 < NCH) {                   // issue next chunk's loads early
      const int dbase = (c + 1) * DC * plane;
      #pragma unroll
      for (int it = 0; it < 2; ++it)
        #pragma unroll
        for (int p = 0; p < 4; ++p)
          s[it][p] = Kb[dbase + sg_g[it] + p * plane];
      #pragma unroll
      for (int p = 0; p < 4; ++p)
        qn[p] = Qb[((c + 1) * DC + dq + p) * plane + qoff];
    }
    const float* __restrict__ bc = buf[cur];
    #pragma unroll
    for (int j = 0; j < 9; ++j) {
      const float4 k4 = *(const float4*)&bc[lofs[j]];
      float acc = logit[j];
      acc = fmaf(q[0], k4.x, acc); acc = fmaf(q[1], k4.y, acc);
      acc = fmaf(q[2], k4.z, acc); acc = fmaf(q[3], k4.w, acc);
      logit[j] = acc;
    }
    if (c + 1 < NCH) {
      #pragma unroll
      for (int it = 0; it < 2; ++it)
        *(float4*)&buf[cur ^ 1][sg_l[it]] = make_float4(s[it][0], s[it][1], s[it][2], s[it][3]);
      #pragma unroll
      for (int p = 0; p < 4; ++p) q[p] = qn[p];
    }
    __syncthreads();
  }

  // issue V chunk-0 staging loads now; softmax math hides their latency
  float vs[2][4];
  #pragma unroll
  for (int it = 0; it < 2; ++it)
    #pragma unroll
    for (int p = 0; p < 4; ++p)
      vs[it][p] = Vb[sg_g[it] + p * plane];

  // quad-reduce partial logits (lanes 4m..4m+3 share a pixel)
  #pragma unroll
  for (int j = 0; j < 9; ++j) {
    logit[j] += __shfl_xor(logit[j], 1);
    logit[j] += __shfl_xor(logit[j], 2);
  }
  // softmax over 9 (OOB logits = 0 participate in denominator)
  #pragma unroll
  for (int j = 0; j < 9; ++j) logit[j] = msk[j] * logit[j] * SCALE;
  float m = logit[0];
  #pragma unroll
  for (int j = 1; j < 9; ++j) m = fmaxf(m, logit[j]);
  float att[9];
  float Z = 0.0f;
  #pragma unroll
  for (int j = 0; j < 9; ++j) { att[j] = __expf(logit[j] - m); Z += att[j]; }
  const float rZ = 1.0f / Z;
  #pragma unroll
  for (int j = 0; j < 9; ++j) att[j] *= rZ * msk[j];

  // ================= Phase 2: PV =================
  // buf[0] reads finished at phase-1's final barrier; stage V chunk 0
  #pragma unroll
  for (int it = 0; it < 2; ++it)
    *(float4*)&buf[0][sg_l[it]] = make_float4(vs[it][0], vs[it][1], vs[it][2], vs[it][3]);
  __syncthreads();

  const size_t obase = ((size_t)b * plane + (size_t)h0 * WW) * HD;
  float oprev[4];
  for (int c = 0; c < NCH; ++c) {
    const int cur = c & 1;
    float s[2][4];
    if (c + 1 < NCH) {
      const int dbase = (c + 1) * DC * plane;
      #pragma unroll
      for (int it = 0; it < 2; ++it)
        #pragma unroll
        for (int p = 0; p < 4; ++p)
          s[it][p] = Vb[dbase + sg_g[it] + p * plane];
    }
    float o0 = 0.f, o1 = 0.f, o2 = 0.f, o3 = 0.f;
    const float* __restrict__ bc = buf[cur];
    #pragma unroll
    for (int j = 0; j < 9; ++j) {
      const float4 v4 = *(const float4*)&bc[lofs[j]];
      const float a = att[j];
      o0 = fmaf(a, v4.x, o0); o1 = fmaf(a, v4.y, o1);
      o2 = fmaf(a, v4.z, o2); o3 = fmaf(a, v4.w, o3);
    }
    if (c & 1) {
      // paired writeout: quad covers planes [ (c-1)*16 .. (c-1)*16+31 ] of its
      // pixel = one full 128B sector
      const size_t oa = obase + (size_t)px * HD + (size_t)(c - 1) * DC + dq;
      *(float4*)&O[oa]      = make_float4(oprev[0], oprev[1], oprev[2], oprev[3]);
      *(float4*)&O[oa + DC] = make_float4(o0, o1, o2, o3);
    } else {
      oprev[0] = o0; oprev[1] = o1; oprev[2] = o2; oprev[3] = o3;
    }
    if (c + 1 < NCH) {
      #pragma unroll
      for (int it = 0; it < 2; ++it)
        *(float4*)&buf[cur ^ 1][sg_l[it]] = make_float4(s[it][0], s[it][1], s[it][2], s[it][3]);
      __syncthreads();
    }
  }
}

extern "C" void kernel_launch(void* const* d_in, const int* in_sizes, int n_in,
                              void* d_out, int out_size, void* d_ws, size_t ws_size,
                              hipStream_t stream) {
  const float* q = (const float*)d_in[0];
  const float* k = (const float*)d_in[1];
  const float* v = (const float*)d_in[2];
  float* o = (float*)d_out;
  const int nblocks = 32 * (HH / ROWS);   // 1024
  natten3_kernel<<<dim3(nblocks), dim3(BLK), 0, stream>>>(q, k, v, o);
}